// Round 1
// baseline (418.559 us; speedup 1.0000x reference)
//
#include <hip/hip_runtime.h>
#include <hip/hip_bf16.h>
#include <math.h>

#define B_   2
#define S_   2048
#define D_   1024
#define H_   16
#define HD_  64
#define DFF_ 4096
#define M_   (B_*S_)   // 4096 rows
#define SCALE_ 0.08838834764831845f  // 1/sqrt(128)

typedef __attribute__((ext_vector_type(8))) short bf16x8;
typedef __attribute__((ext_vector_type(4))) float f32x4;

#define MFMA16(a,b,c) __builtin_amdgcn_mfma_f32_16x16x32_bf16((a),(b),(c),0,0,0)

__device__ __forceinline__ unsigned short f2b(float f) {
    union { float f; unsigned u; } v; v.f = f;
    return (unsigned short)((v.u + 0x7FFFu + ((v.u >> 16) & 1u)) >> 16);
}
__device__ __forceinline__ float b2f(unsigned short s) {
    union { unsigned u; float f; } v; v.u = ((unsigned)s) << 16;
    return v.f;
}
// pack two f32 -> two bf16 (truncating) in ONE v_perm_b32
__device__ __forceinline__ unsigned pk2bf(float a, float b) {
    union { float f; unsigned u; } ua, ub; ua.f = a; ub.f = b;
    return __builtin_amdgcn_perm(ub.u, ua.u, 0x07060302u);
}
__device__ __forceinline__ float softplus_f(float x) {
    return fmaxf(x, 0.f) + log1pf(__expf(-fabsf(x)));
}
// async global->LDS, 16B per lane. LDS dest = base + lane*16 (wave-uniform base).
__device__ __forceinline__ void g2l16(const void* g, void* l) {
    __builtin_amdgcn_global_load_lds(
        (const __attribute__((address_space(1))) unsigned int*)g,
        (__attribute__((address_space(3))) unsigned int*)l, 16, 0, 0);
}

// ---------------------------------------------------------------------------
__global__ __launch_bounds__(256) void conv_bf16_kernel(
    const float* __restrict__ in, unsigned short* __restrict__ out)
{
    int i = (blockIdx.x * 256 + threadIdx.x) * 4;
    float4 v = *(const float4*)&in[i];
    ushort4 o;
    o.x = f2b(v.x); o.y = f2b(v.y); o.z = f2b(v.z); o.w = f2b(v.w);
    *(ushort4*)&out[i] = o;
}

// ---------------------------------------------------------------------------
// Weight transpose + bf16: W[K][N] fp32 -> WT[N][K] bf16
// ---------------------------------------------------------------------------
__global__ __launch_bounds__(256) void wtrans_kernel(
    const float* __restrict__ W, unsigned short* __restrict__ WT, int K, int N)
{
    __shared__ float tile[32][33];
    const int n0 = blockIdx.x * 32, k0 = blockIdx.y * 32;
    const int tx = threadIdx.x & 31, ty = threadIdx.x >> 5;  // ty 0..7
    #pragma unroll
    for (int i = 0; i < 4; i++)
        tile[ty + 8*i][tx] = W[(size_t)(k0 + ty + 8*i) * N + n0 + tx];
    __syncthreads();
    #pragma unroll
    for (int i = 0; i < 4; i++)
        WT[(size_t)(n0 + ty + 8*i) * K + k0 + tx] = f2b(tile[tx][ty + 8*i]);
}

// Fused transpose of the four 1024x1024 square weights (saves 3 launches).
__global__ __launch_bounds__(256) void wtrans4_kernel(
    const float* __restrict__ Wa, const float* __restrict__ Wb,
    const float* __restrict__ Wc, const float* __restrict__ Wd,
    unsigned short* __restrict__ Tabc, unsigned short* __restrict__ Td)
{
    __shared__ float tile[32][33];
    const int z = blockIdx.z;
    const float* W = (z == 0) ? Wa : (z == 1) ? Wb : (z == 2) ? Wc : Wd;
    unsigned short* WT = (z < 3) ? Tabc + (size_t)z * 1024 * 1024 : Td;
    const int n0 = blockIdx.x * 32, k0 = blockIdx.y * 32;
    const int tx = threadIdx.x & 31, ty = threadIdx.x >> 5;
    #pragma unroll
    for (int i = 0; i < 4; i++)
        tile[ty + 8*i][tx] = W[(size_t)(k0 + ty + 8*i) * 1024 + n0 + tx];
    __syncthreads();
    #pragma unroll
    for (int i = 0; i < 4; i++)
        WT[(size_t)(n0 + ty + 8*i) * 1024 + k0 + tx] = f2b(tile[tx][ty + 8*i]);
}

// ---------------------------------------------------------------------------
__global__ __launch_bounds__(256) void bcat_kernel(
    const float* __restrict__ a, const float* __restrict__ b,
    const float* __restrict__ c, float* __restrict__ o)
{
    int i = blockIdx.x * 256 + threadIdx.x;
    o[i] = (i < 1024) ? a[i] : (i < 2048 ? b[i - 1024] : c[i - 2048]);
}

// ---------------------------------------------------------------------------
// bf16 GEMM, 128^2 tile, BK=64, XOR-swizzled LDS, double-buffered staging,
// XCD-aware remap, optional split-K. Kept for Wo / W2 (N=1024 shapes).
// ---------------------------------------------------------------------------
__global__ __launch_bounds__(256) void gemm_bf16_kernel(
    const unsigned short* __restrict__ A,
    const unsigned short* __restrict__ WT,
    const float* __restrict__ bias,
    float* __restrict__ outF, unsigned short* __restrict__ outB,
    int M, int Kslice, int lda, int N, int relu)
{
    __shared__ unsigned short As[2][128 * 64];
    __shared__ unsigned short Bs[2][128 * 64];

    const int tid = threadIdx.x;
    const int w = tid >> 6, lane = tid & 63;
    const int quad = lane >> 4, l16 = lane & 15;

    const int nn = gridDim.x, nm = gridDim.y;
    const int lin = ((int)blockIdx.z * nm + (int)blockIdx.y) * nn + (int)blockIdx.x;
    const int per = (nn * nm * (int)gridDim.z) >> 3;
    const int id  = (lin & 7) * per + (lin >> 3);
    const int zz  = id / (nn * nm);
    const int rem = id - zz * nn * nm;
    const int mt_ = rem / nn, nt_ = rem - mt_ * nn;

    const size_t m0 = (size_t)mt_ * 128, n0 = (size_t)nt_ * 128;
    const int wm = (w >> 1) * 64, wn = (w & 1) * 64;
    const int koff = zz * Kslice;

    const int srow = lane >> 3;                       // 0..7 row within group
    const int sc   = ((lane & 7) ^ srow) * 8;         // swizzled global chunk
    const unsigned short* ga = A  + (m0 + w * 32 + srow) * (size_t)lda + koff + sc;
    const unsigned short* gb = WT + (n0 + w * 32 + srow) * (size_t)lda + koff + sc;
    const size_t rows8 = (size_t)8 * lda;

    f32x4 acc[4][4] = {};
    const int niter = Kslice >> 6;

    #pragma unroll
    for (int j = 0; j < 4; j++) g2l16(ga + j * rows8, &As[0][(w * 32 + j * 8) * 64]);
    #pragma unroll
    for (int j = 0; j < 4; j++) g2l16(gb + j * rows8, &Bs[0][(w * 32 + j * 8) * 64]);

    for (int i = 0; i < niter; i++) {
        __syncthreads();
        if (i + 1 < niter) {
            const int nb = (i + 1) & 1, k0 = (i + 1) << 6;
            #pragma unroll
            for (int j = 0; j < 4; j++)
                g2l16(ga + j * rows8 + k0, &As[nb][(w * 32 + j * 8) * 64]);
            #pragma unroll
            for (int j = 0; j < 4; j++)
                g2l16(gb + j * rows8 + k0, &Bs[nb][(w * 32 + j * 8) * 64]);
        }
        const int buf = i & 1;

        #pragma unroll
        for (int kk = 0; kk < 2; kk++) {
            bf16x8 af[4], bfr[4];
            #pragma unroll
            for (int t = 0; t < 4; t++) {
                const int slot = ((kk * 4 + quad) ^ (l16 & 7)) * 8;
                af[t]  = *(const bf16x8*)&As[buf][(wm + t * 16 + l16) * 64 + slot];
                bfr[t] = *(const bf16x8*)&Bs[buf][(wn + t * 16 + l16) * 64 + slot];
            }
            #pragma unroll
            for (int mt = 0; mt < 4; mt++)
                #pragma unroll
                for (int nt = 0; nt < 4; nt++)
                    acc[mt][nt] = MFMA16(af[mt], bfr[nt], acc[mt][nt]);
        }
    }

    float bv[4];
    #pragma unroll
    for (int nt = 0; nt < 4; nt++)
        bv[nt] = (zz == 0) ? bias[n0 + wn + nt * 16 + l16] : 0.f;

    float* outFz = outF ? outF + (size_t)zz * M * N : nullptr;

    #pragma unroll
    for (int mt = 0; mt < 4; mt++) {
        #pragma unroll
        for (int nt = 0; nt < 4; nt++) {
            const size_t n = n0 + wn + nt * 16 + l16;
            #pragma unroll
            for (int r = 0; r < 4; r++) {
                const size_t m = m0 + wm + mt * 16 + quad * 4 + r;
                float val = acc[mt][nt][r] + bv[nt];
                if (relu) val = fmaxf(val, 0.f);
                const size_t idx = m * N + n;
                if (outFz) outFz[idx] = val;
                if (outB) outB[idx] = f2b(val);
            }
        }
    }
}

// ---------------------------------------------------------------------------
// bf16 GEMM, 256^2 tile, BK=64, 8 waves (2M x 4N), 8-phase schedule with
// counted vmcnt (T2+T3+T4+T5 per the verified 256^2 template):
//   per K-tile, 4 phases: {ds_read subtile; issue 1 half-tile stage;
//   s_barrier; lgkmcnt(0); setprio(1); 16 MFMA (one C-quadrant x K=64);
//   setprio(0); s_barrier}. vmcnt(4) once per K-tile (never 0 mid-loop).
// A staged 1 tile ahead (A-half slot free after phi2), B staged 2 tiles
// ahead (B-half slot free after phi1). Requires Kslice % 128 == 0,
// M % 256 == 0, N % 256 == 0, grid blocks % 8 == 0.
// ---------------------------------------------------------------------------
__global__ __launch_bounds__(512, 2) void gemm256_bf16_kernel(
    const unsigned short* __restrict__ A,
    const unsigned short* __restrict__ WT,
    const float* __restrict__ bias,
    float* __restrict__ outF, unsigned short* __restrict__ outB,
    int M, int Kslice, int lda, int N, int relu)
{
    __shared__ unsigned short As[2][256 * 64];   // 64 KiB
    __shared__ unsigned short Bs[2][256 * 64];   // 64 KiB

    const int tid = threadIdx.x;
    const int w = tid >> 6, lane = tid & 63;
    const int quad = lane >> 4, l16 = lane & 15;
    const int wm_ = w >> 2, wn_ = w & 3;          // 2 x 4 wave grid

    // XCD-aware remap (total blocks divisible by 8)
    const int nn = gridDim.x, nm = gridDim.y;
    const int lin = ((int)blockIdx.z * nm + (int)blockIdx.y) * nn + (int)blockIdx.x;
    const int per = (nn * nm * (int)gridDim.z) >> 3;
    const int id  = (lin & 7) * per + (lin >> 3);
    const int zz  = id / (nn * nm);
    const int rem = id - zz * nn * nm;
    const int mt_ = rem / nn, nt_ = rem - mt_ * nn;

    const size_t m0 = (size_t)mt_ * 256, n0 = (size_t)nt_ * 256;
    const int koff = zz * Kslice;

    // staging: each g2l16 covers 8 rows x 64 cols; wave w -> rows [w*8, w*8+8)
    // within a 64-row group; 2 calls per 128-row half-tile.
    const int srow = lane >> 3;
    const int sc   = ((lane & 7) ^ srow) * 8;     // pre-swizzled source chunk
    const unsigned short* ga = A  + (m0 + w * 8 + srow) * (size_t)lda + koff + sc;
    const unsigned short* gb = WT + (n0 + w * 8 + srow) * (size_t)lda + koff + sc;
    const size_t rows64    = (size_t)64 * lda;
    const size_t half_rows = (size_t)128 * lda;

    // ds_read slots (element offsets within a 64-elem row)
    const int s0 = (quad ^ (l16 & 7)) * 8;        // kk=0
    const int s1 = s0 ^ 32;                       // kk=1

    const int niter = Kslice >> 6;                // even (Kslice % 128 == 0)

#define STAGE_A(BUF, T, H) do { \
    const size_t k0_ = (size_t)(T) << 6; \
    g2l16(ga + (size_t)(H) * half_rows + k0_,          &As[BUF][((H) * 128 + w * 8) * 64]); \
    g2l16(ga + (size_t)(H) * half_rows + rows64 + k0_, &As[BUF][((H) * 128 + 64 + w * 8) * 64]); \
} while (0)

#define STAGE_B(BUF, T, H) do { \
    const size_t k0_ = (size_t)(T) << 6; \
    g2l16(gb + (size_t)(H) * half_rows + k0_,          &Bs[BUF][((H) * 128 + w * 8) * 64]); \
    g2l16(gb + (size_t)(H) * half_rows + rows64 + k0_, &Bs[BUF][((H) * 128 + 64 + w * 8) * 64]); \
} while (0)

#define RD_A(DST, BUF, MROW, KK) \
    DST = *(const bf16x8*)&As[BUF][(wm_ * 128 + (MROW) * 16 + l16) * 64 + ((KK) ? s1 : s0)]
#define RD_B(DST, BUF, NROW, KK) \
    DST = *(const bf16x8*)&Bs[BUF][(wn_ * 64 + (NROW) * 16 + l16) * 64 + ((KK) ? s1 : s0)]

#define MM8(MOFF, NOFF, AR, BR) do { \
    _Pragma("unroll") \
    for (int kk_ = 0; kk_ < 2; ++kk_) { \
        _Pragma("unroll") \
        for (int mf_ = 0; mf_ < 4; ++mf_) { \
            _Pragma("unroll") \
            for (int nf_ = 0; nf_ < 2; ++nf_) \
                acc[(MOFF) + mf_][(NOFF) + nf_] = \
                    MFMA16(AR[mf_][kk_], BR[nf_][kk_], acc[(MOFF) + mf_][(NOFF) + nf_]); \
        } \
    } \
} while (0)

    f32x4 acc[8][4] = {};
    bf16x8 a_lo[4][2], b_lo[2][2];
    bf16x8 a_hi[4][2] = {};   // zero: phi0 MFMA of period 0 adds 0
    bf16x8 b_hi[2][2] = {};

    // prologue: B0, A0, B1 (12 loads); leave newest 4 (B1) in flight.
    STAGE_B(0, 0, 0); STAGE_B(0, 0, 1);
    STAGE_A(0, 0, 0); STAGE_A(0, 0, 1);
    STAGE_B(1, 1, 0); STAGE_B(1, 1, 1);
    asm volatile("s_waitcnt vmcnt(4)" ::: "memory");
    __builtin_amdgcn_s_barrier();

#define PERIOD(BUF, T) do { \
    const int t_ = (T); \
    /* phi0: read A[m0-3], B[n0-1]; stage A_{t+1}h0; MFMA q3(t-1) */ \
    RD_A(a_lo[0][0], BUF, 0, 0); RD_A(a_lo[0][1], BUF, 0, 1); \
    RD_A(a_lo[1][0], BUF, 1, 0); RD_A(a_lo[1][1], BUF, 1, 1); \
    RD_A(a_lo[2][0], BUF, 2, 0); RD_A(a_lo[2][1], BUF, 2, 1); \
    RD_A(a_lo[3][0], BUF, 3, 0); RD_A(a_lo[3][1], BUF, 3, 1); \
    RD_B(b_lo[0][0], BUF, 0, 0); RD_B(b_lo[0][1], BUF, 0, 1); \
    RD_B(b_lo[1][0], BUF, 1, 0); RD_B(b_lo[1][1], BUF, 1, 1); \
    if (t_ + 1 < niter) STAGE_A((BUF) ^ 1, t_ + 1, 0); \
    __builtin_amdgcn_s_barrier(); \
    asm volatile("s_waitcnt lgkmcnt(0)" ::: "memory"); \
    __builtin_amdgcn_s_setprio(1); \
    MM8(4, 2, a_hi, b_hi); \
    __builtin_amdgcn_s_setprio(0); \
    __builtin_amdgcn_s_barrier(); \
    /* phi1: read B[n2-3]; stage A_{t+1}h1; MFMA q0(t) */ \
    RD_B(b_hi[0][0], BUF, 2, 0); RD_B(b_hi[0][1], BUF, 2, 1); \
    RD_B(b_hi[1][0], BUF, 3, 0); RD_B(b_hi[1][1], BUF, 3, 1); \
    if (t_ + 1 < niter) STAGE_A((BUF) ^ 1, t_ + 1, 1); \
    __builtin_amdgcn_s_barrier(); \
    asm volatile("s_waitcnt lgkmcnt(0)" ::: "memory"); \
    __builtin_amdgcn_s_setprio(1); \
    MM8(0, 0, a_lo, b_lo); \
    __builtin_amdgcn_s_setprio(0); \
    __builtin_amdgcn_s_barrier(); \
    /* phi2: read A[m4-7]; stage B_{t+2}h0; MFMA q1(t) */ \
    RD_A(a_hi[0][0], BUF, 4, 0); RD_A(a_hi[0][1], BUF, 4, 1); \
    RD_A(a_hi[1][0], BUF, 5, 0); RD_A(a_hi[1][1], BUF, 5, 1); \
    RD_A(a_hi[2][0], BUF, 6, 0); RD_A(a_hi[2][1], BUF, 6, 1); \
    RD_A(a_hi[3][0], BUF, 7, 0); RD_A(a_hi[3][1], BUF, 7, 1); \
    if (t_ + 2 < niter) STAGE_B(BUF, t_ + 2, 0); \
    __builtin_amdgcn_s_barrier(); \
    asm volatile("s_waitcnt lgkmcnt(0)" ::: "memory"); \
    __builtin_amdgcn_s_setprio(1); \
    MM8(0, 2, a_lo, b_hi); \
    __builtin_amdgcn_s_setprio(0); \
    __builtin_amdgcn_s_barrier(); \
    /* phi3: stage B_{t+2}h1; MFMA q2(t); counted vmcnt */ \
    if (t_ + 2 < niter) STAGE_B(BUF, t_ + 2, 1); \
    __builtin_amdgcn_s_barrier(); \
    __builtin_amdgcn_s_setprio(1); \
    MM8(4, 0, a_hi, b_lo); \
    __builtin_amdgcn_s_setprio(0); \
    if (t_ + 2 < niter) { asm volatile("s_waitcnt vmcnt(4)" ::: "memory"); } \
    else                { asm volatile("s_waitcnt vmcnt(0)" ::: "memory"); } \
    __builtin_amdgcn_s_barrier(); \
} while (0)

    for (int t = 0; t < niter; t += 2) {
        PERIOD(0, t);
        PERIOD(1, t + 1);
    }
    // leftover q3 of the last K-tile (all operands in registers)
    MM8(4, 2, a_hi, b_hi);

    float bv[4];
    #pragma unroll
    for (int nf = 0; nf < 4; nf++)
        bv[nf] = (zz == 0) ? bias[n0 + wn_ * 64 + nf * 16 + l16] : 0.f;

    float* outFz = outF ? outF + (size_t)zz * M * N : nullptr;

    #pragma unroll
    for (int mf = 0; mf < 8; mf++) {
        #pragma unroll
        for (int nf = 0; nf < 4; nf++) {
            const size_t n = n0 + wn_ * 64 + nf * 16 + l16;
            #pragma unroll
            for (int r = 0; r < 4; r++) {
                const size_t m = m0 + wm_ * 128 + mf * 16 + quad * 4 + r;
                float val = acc[mf][nf][r] + bv[nf];
                if (relu) val = fmaxf(val, 0.f);
                const size_t idx = m * N + n;
                if (outFz) outFz[idx] = val;
                if (outB) outB[idx] = f2b(val);
            }
        }
    }

#undef STAGE_A
#undef STAGE_B
#undef RD_A
#undef RD_B
#undef MM8
#undef PERIOD
}

// ---------------------------------------------------------------------------
// PoPE: qkvb bf16 (B,S,3072) -> bf16 qp,kp (B*H, S, 128). Q pre-scaled.
// ---------------------------------------------------------------------------
__global__ __launch_bounds__(256) void pope_kernel(
    const unsigned short* __restrict__ qkv,
    const float* __restrict__ phase_bias, const float* __restrict__ freqs,
    unsigned short* __restrict__ qp, unsigned short* __restrict__ kp)
{
    int idx = blockIdx.x * 256 + threadIdx.x;   // over B*H*S*HD = 4M
    int d = idx & 63;
    int s = (idx >> 6) & (S_ - 1);
    int h = (idx >> 17) & (H_ - 1);
    int b = idx >> 21;

    size_t src = (size_t)(b * S_ + s) * 3072 + h * HD_ + d;
    float muq = softplus_f(b2f(qkv[src])) * SCALE_;
    float muk = softplus_f(b2f(qkv[src + 1024]));

    float ph = (float)s * freqs[d] + phase_bias[h * HD_ + d];
    float sn, cs;
    sincosf(ph, &sn, &cs);

    size_t o = ((size_t)(b * H_ + h) * S_ + s) * 128 + d;
    qp[o]      = f2b(muq * cs);
    qp[o + 64] = f2b(muq * sn);
    kp[o]      = f2b(muk * cs);
    kp[o + 64] = f2b(muk * sn);
}

// ---------------------------------------------------------------------------
// V transpose: qkvb bf16 (B,S,3072) col 2048.. -> vt bf16 (B*H, 64, S)
// ---------------------------------------------------------------------------
__global__ __launch_bounds__(256) void vtrans_kernel(
    const unsigned short* __restrict__ qkv, unsigned short* __restrict__ vt)
{
    __shared__ unsigned short tile[64][72];
    const int bh = blockIdx.y, b = bh >> 4, h = bh & 15;
    const int s0 = blockIdx.x * 64;
    const int tid = threadIdx.x;
    #pragma unroll
    for (int i = 0; i < 16; i++) {
        int idx = i * 256 + tid;
        int s = idx >> 6, d = idx & 63;
        tile[s][d] = qkv[(size_t)(b * S_ + s0 + s) * 3072 + 2048 + h * HD_ + d];
    }
    __syncthreads();
    #pragma unroll
    for (int i = 0; i < 16; i++) {
        int idx = i * 256 + tid;
        int d = idx >> 6, s = idx & 63;
        vt[((size_t)bh * 64 + d) * S_ + s0 + s] = tile[s][d];
    }
}

// ---------------------------------------------------------------------------
// MFMA flash attention: softmax1, lazy normalization, S^T trick,
// 128 q rows/block, dbuf K/V staging, causal split over grid.z.
// ---------------------------------------------------------------------------
__global__ __launch_bounds__(512, 4) void attn_mfma_kernel(
    const unsigned short* __restrict__ qp,
    const unsigned short* __restrict__ kp,
    const unsigned short* __restrict__ vt,
    unsigned short* __restrict__ ao)
{
    __shared__ unsigned short kt_lds[2][64][128];  // [buf][key][k], chunk^=(key&15)
    __shared__ unsigned short vt_lds[2][64][64];   // [buf][d][key], chunk^=(d&7)
    __shared__ unsigned short p_lds[8][16][72];    // per-wave P: [q][key]

    const int tid = threadIdx.x;
    const int w = tid >> 6, lane = tid & 63;
    const int quad = lane >> 4, l16 = lane & 15;
    const int bh = blockIdx.y, b = bh >> 4, h = bh & 15;

    const int a = (blockIdx.z == 0) ? 15 - (int)blockIdx.x : (int)blockIdx.x;
    const int q0b = a * 128;
    const int q0 = q0b + w * 16;

    const unsigned short* qbase = qp + ((size_t)bh * S_ + q0 + l16) * 128 + quad * 8;
    bf16x8 qa[4];
    #pragma unroll
    for (int kc = 0; kc < 4; kc++) qa[kc] = *(const bf16x8*)(qbase + kc * 32);

    const int krow = lane >> 4, kslot = lane & 15;
    const int vrow = lane >> 3, vslot = lane & 7;
    const int kr0 = w * 8 + krow,     kc0 = kslot ^ (kr0 & 15);
    const int kr1 = w * 8 + 4 + krow, kc1 = kslot ^ (kr1 & 15);
    const int vd  = w * 8 + vrow,     vc  = vslot ^ (vd & 7);
    const unsigned short* kg0 = kp + ((size_t)bh * S_ + kr0) * 128 + kc0 * 8;
    const unsigned short* kg1 = kp + ((size_t)bh * S_ + kr1) * 128 + kc1 * 8;
    const unsigned short* vg0 = vt + ((size_t)bh * 64 + vd) * S_ + vc * 8;

    f32x4 o[4] = {};
    float ms = -1e30f, ls = 0.f;

    const int ntiles = 2 * a + 2;

    g2l16(kg0, &kt_lds[0][w * 8][0]);
    g2l16(kg1, &kt_lds[0][w * 8 + 4][0]);
    g2l16(vg0, &vt_lds[0][w * 8][0]);

    for (int ti = 0; ti < ntiles; ti++) {
        const int t0 = ti * 64;
        __syncthreads();
        if (ti + 1 < ntiles) {
            const int nb = (ti + 1) & 1;
            const size_t ko = (size_t)(ti + 1) * (64 * 128);
            const size_t vo = (size_t)(ti + 1) * 64;
            g2l16(kg0 + ko, &kt_lds[nb][w * 8][0]);
            g2l16(kg1 + ko, &kt_lds[nb][w * 8 + 4][0]);
            g2l16(vg0 + vo, &vt_lds[nb][w * 8][0]);
        }
        const int buf = ti & 1;

        if (t0 <= q0 + 15) {
            f32x4 sf[4];
            #pragma unroll
            for (int kg = 0; kg < 4; kg++) {
                f32x4 s = {0, 0, 0, 0};
                const int row = kg * 16 + l16;
                #pragma unroll
                for (int kc = 0; kc < 4; kc++) {
                    const int slot = (kc * 4 + quad) ^ l16;
                    s = MFMA16(*(const bf16x8*)&kt_lds[buf][row][slot * 8], qa[kc], s);
                }
                sf[kg] = s;
            }

            const int qrow = q0 + l16;
            const bool dmask = (t0 + 63 > q0);
            #pragma unroll
            for (int kg = 0; kg < 4; kg++) {
                const int kbase = t0 + kg * 16 + quad * 4;
                float v0 = sf[kg][0], v1 = sf[kg][1], v2 = sf[kg][2], v3 = sf[kg][3];
                if (dmask) {
                    v0 = (kbase     <= qrow) ? v0 : -1e30f;
                    v1 = (kbase + 1 <= qrow) ? v1 : -1e30f;
                    v2 = (kbase + 2 <= qrow) ? v2 : -1e30f;
                    v3 = (kbase + 3 <= qrow) ? v3 : -1e30f;
                }
                ms = fmaxf(ms, fmaxf(fmaxf(v0, v1), fmaxf(v2, v3)));
                const float e0 = __expf(v0), e1 = __expf(v1);
                const float e2 = __expf(v2), e3 = __expf(v3);
                ls += (e0 + e1) + (e2 + e3);
                uint2 pk;
                pk.x = pk2bf(e0, e1);
                pk.y = pk2bf(e2, e3);
                *(uint2*)&p_lds[w][l16][kg * 16 + quad * 4] = pk;
            }
            asm volatile("s_waitcnt lgkmcnt(0)" ::: "memory");
            bf16x8 pa0 = *(const bf16x8*)&p_lds[w][l16][quad * 8];
            bf16x8 pa1 = *(const bf16x8*)&p_lds[w][l16][quad * 8 + 32];

            #pragma unroll
            for (int dg = 0; dg < 4; dg++) {
                const int row = dg * 16 + l16;
                const int s0_ = quad ^ (l16 & 7);
                const int s1_ = (quad + 4) ^ (l16 & 7);
                o[dg] = MFMA16(pa0, *(const bf16x8*)&vt_lds[buf][row][s0_ * 8], o[dg]);
                o[dg] = MFMA16(pa1, *(const bf16x8*)&vt_lds[buf][row][s1_ * 8], o[dg]);
            }
        }
    }

    float mv = ms, lv = ls;
    mv = fmaxf(mv, __shfl_xor(mv, 16, 64)); lv += __shfl_xor(lv, 16, 64);
    mv = fmaxf(mv, __shfl_xor(mv, 32, 64)); lv += __shfl_xor(lv, 32, 64);
    const float inv = 1.f / (__expf(mv) + lv);

    #pragma unroll
    for (int r = 0; r < 4; r++) {
        const float ir = __shfl(inv, quad * 4 + r, 64);
        const int row = q0 + quad * 4 + r;
        const size_t base = (size_t)(b * S_ + row) * D_ + h * HD_ + l16;
        ao[base]      = f2b(o[0][r] * ir);
        ao[base + 16] = f2b(o[1][r] * ir);
        ao[base + 32] = f2b(o[2][r] * ir);
        ao[base + 48] = f2b(o[3][r] * ir);
    }
}

// ---------------------------------------------------------------------------
// Residual + LayerNorm over (ya + yb + res); residual fp32 OR bf16;
// outputs fp32 and/or bf16 (either may be null).
// ---------------------------------------------------------------------------
__global__ __launch_bounds__(256) void ln_kernel(
    const float* __restrict__ ya, const float* __restrict__ yb,
    const float* __restrict__ resF, const unsigned short* __restrict__ resB,
    const float* __restrict__ g, const float* __restrict__ beta,
    float* __restrict__ outF, unsigned short* __restrict__ outB)
{
    const int row = blockIdx.x;
    const int tid = threadIdx.x;
    const float* yr = ya + (size_t)row * D_;
    const float* y2 = yb ? yb + (size_t)row * D_ : nullptr;

    float t[4];
    float sum = 0.f, sumsq = 0.f;
    #pragma unroll
    for (int i = 0; i < 4; i++) {
        int c = tid + 256 * i;
        float rv = resF ? resF[(size_t)row * D_ + c] : b2f(resB[(size_t)row * D_ + c]);
        t[i] = yr[c] + rv + (y2 ? y2[c] : 0.f);
        sum += t[i]; sumsq += t[i] * t[i];
    }
    #pragma unroll
    for (int off = 32; off >= 1; off >>= 1) {
        sum   += __shfl_xor(sum,   off, 64);
        sumsq += __shfl_xor(sumsq, off, 64);
    }
    __shared__ float rs_[4], rq_[4];
    int w = tid >> 6, lane = tid & 63;
    if (lane == 0) { rs_[w] = sum; rq_[w] = sumsq; }
    __syncthreads();
    float tot  = rs_[0] + rs_[1] + rs_[2] + rs_[3];
    float totq = rq_[0] + rq_[1] + rq_[2] + rq_[3];
    float mu   = tot  * (1.f / D_);
    float var  = totq * (1.f / D_) - mu * mu;
    float rstd = rsqrtf(var + 1e-5f);

    #pragma unroll
    for (int i = 0; i < 4; i++) {
        int c = tid + 256 * i;
        float val = (t[i] - mu) * rstd * g[c] + beta[c];
        if (outF) outF[(size_t)row * D_ + c] = val;
        if (outB) outB[(size_t)row * D_ + c] = f2b(val);
    }
}

// ---------------------------------------------------------------------------
extern "C" void kernel_launch(void* const* d_in, const int* in_sizes, int n_in,
                              void* d_out, int out_size, void* d_ws, size_t ws_size,
                              hipStream_t stream)
{
    const float* x   = (const float*)d_in[0];
    const float* Wq  = (const float*)d_in[2];
    const float* bq  = (const float*)d_in[3];
    const float* Wk  = (const float*)d_in[4];
    const float* bk  = (const float*)d_in[5];
    const float* Wv  = (const float*)d_in[6];
    const float* bv  = (const float*)d_in[7];
    const float* Wo  = (const float*)d_in[8];
    const float* bo  = (const float*)d_in[9];
    const float* phase_bias = (const float*)d_in[10];
    const float* freqs = (const float*)d_in[11];
    const float* W1  = (const float*)d_in[12];
    const float* b1  = (const float*)d_in[13];
    const float* W2  = (const float*)d_in[14];
    const float* b2  = (const float*)d_in[15];
    const float* g1  = (const float*)d_in[16];
    const float* be1 = (const float*)d_in[17];
    const float* g2  = (const float*)d_in[18];
    const float* be2 = (const float*)d_in[19];
    float* out = (float*)d_out;

    char* base = (char*)d_ws;
    const size_t MiB = 1024 * 1024;
    unsigned short* WqkvT = (unsigned short*)(base);             // [0,6)
    unsigned short* WoT   = (unsigned short*)(base + 6  * MiB);  // [6,8)
    unsigned short* W1T   = (unsigned short*)(base + 8  * MiB);  // [8,16)
    unsigned short* W2T   = (unsigned short*)(base + 16 * MiB);  // [16,24)
    float*          bqkv  = (float*)(base + 24 * MiB);           // [24,25)
    unsigned short* xb    = (unsigned short*)(base + 25 * MiB);  // [25,33)
    unsigned short* qkvb  = (unsigned short*)(base + 33 * MiB);  // [33,57)
    unsigned short* qpb   = (unsigned short*)(base + 57 * MiB);  // [57,73)
    unsigned short* kpb   = (unsigned short*)(base + 73 * MiB);  // [73,89)
    unsigned short* vtb   = (unsigned short*)(base + 89 * MiB);  // [89,97)
    float*          po    = (float*)(base + 89 * MiB);           // [89,121) 2 slices (vtb dead)
    unsigned short* aob   = xb;                                  // xb dead after QKV gemm
    unsigned short* x1b   = xb;                                  // aob dead after Wo gemm
    unsigned short* hb    = qkvb;                                // [33,65): qkvb+qpb dead
    float*          fo    = po;                                  // po dead after LN1

    dim3 blk(256);

    // prep
    conv_bf16_kernel<<<dim3(M_ * D_ / 1024), blk, 0, stream>>>(x, xb);
    wtrans4_kernel<<<dim3(32, 32, 4), blk, 0, stream>>>(Wq, Wk, Wv, Wo, WqkvT, WoT);
    wtrans_kernel<<<dim3(DFF_ / 32, D_ / 32), blk, 0, stream>>>(W1, W1T, D_, DFF_);
    wtrans_kernel<<<dim3(D_ / 32, DFF_ / 32), blk, 0, stream>>>(W2, W2T, DFF_, D_);
    bcat_kernel<<<dim3(12), blk, 0, stream>>>(bq, bk, bv, bqkv);

    // fused QKV projection -> bf16 qkvb (256^2 8-phase, 12x16=192 blocks)
    gemm256_bf16_kernel<<<dim3(3072 / 256, M_ / 256, 1), dim3(512), 0, stream>>>(
        xb, WqkvT, bqkv, nullptr, qkvb, M_, D_, D_, 3072, 0);

    // PoPE + V transpose
    pope_kernel<<<dim3(B_ * H_ * S_ * HD_ / 256), blk, 0, stream>>>(
        qkvb, phase_bias, freqs, qpb, kpb);
    vtrans_kernel<<<dim3(S_ / 64, B_ * H_), blk, 0, stream>>>(qkvb, vtb);

    // Flash attention
    attn_mfma_kernel<<<dim3(8, B_ * H_, 2), dim3(512), 0, stream>>>(qpb, kpb, vtb, aob);

    // Output projection (split-K=2, 128^2 kernel) + LN1 (bf16-only output)
    gemm_bf16_kernel<<<dim3(D_ / 128, M_ / 128, 2), blk, 0, stream>>>(
        aob, WoT, bo, po, nullptr, M_, D_ / 2, D_, D_, 0);
    ln_kernel<<<dim3(M_), blk, 0, stream>>>(
        po, po + (size_t)M_ * D_, x, nullptr, g1, be1, nullptr, x1b);

    // FFN: W1 on 256^2 8-phase (16x16=256 blocks), W2 on 128^2 split-K=2
    gemm256_bf16_kernel<<<dim3(DFF_ / 256, M_ / 256, 1), dim3(512), 0, stream>>>(
        x1b, W1T, b1, nullptr, hb, M_, D_, D_, DFF_, 1);
    gemm_bf16_kernel<<<dim3(D_ / 128, M_ / 128, 2), blk, 0, stream>>>(
        hb, W2T, b2, fo, nullptr, M_, DFF_ / 2, DFF_, D_, 0);
    ln_kernel<<<dim3(M_), blk, 0, stream>>>(
        fo, fo + (size_t)M_ * D_, nullptr, x1b, g2, be2, out, nullptr);
}